// Round 1
// 413.895 us; speedup vs baseline: 1.0210x; 1.0210x over previous
//
#include <hip/hip_runtime.h>
#include <hip/hip_bf16.h>

typedef __hip_bfloat16 bf16;

constexpr int NN = 50000;           // nodes
constexpr int NE = 800000;          // edges (without self loops)
constexpr int NT = NE + NN;         // edges incl self loops
constexpr int NNB  = (NN + 127)/128; // 391 fill buckets (128 dsts each)
constexpr int NPART = 8;             // XCD partitions (blockIdx & 7)
constexpr int PCAP = 512;            // slots per (bucket, partition); mean 256, 16 sigma

// flag-selected load: f32 storage vs bf16 storage
__device__ __forceinline__ float cvt(const void* p, long long i, int f32){
  return f32 ? ((const float*)p)[i] : __bfloat162float(((const bf16*)p)[i]);
}
// bf16 <-> f32 (RNE pack)
__device__ __forceinline__ unsigned short f2bf(float f){
  unsigned u = __float_as_uint(f);
  u += 0x7fffu + ((u >> 16) & 1);
  return (unsigned short)(u >> 16);
}
__device__ __forceinline__ float bflo(unsigned p){ return __uint_as_float(p << 16); }
__device__ __forceinline__ float bfhi(unsigned p){ return __uint_as_float(p & 0xffff0000u); }
// monotone float<->uint key for atomicMax
__device__ __forceinline__ unsigned f2key(float f){
  unsigned u = __float_as_uint(f);
  return (u & 0x80000000u) ? ~u : (u | 0x80000000u);
}
__device__ __forceinline__ float key2f(unsigned k){
  unsigned u = (k & 0x80000000u) ? (k & 0x7fffffffu) : ~k;
  return __uint_as_float(u);
}

struct SrcPtrs { const void* p[12]; };
// Weight conversion with per-block self-detection of storage dtype
// (flag=1 => f32 storage, 0 => bf16). Block 0 publishes flag for later kernels.
__global__ void k_cvtall(SrcPtrs sp, float* __restrict__ Wc, int* __restrict__ flag){
  const int sz[12]  = {8192,64,4096,64,8192,128,128,128,8192,64,64,32};
  const int off[12] = {0,8192,8256,12352,12416,20608,20736,20864,20992,29184,29248,29312};
  __shared__ int bad;
  if(threadIdx.x == 0) bad = 0;
  __syncthreads();
  const unsigned short* q = (const unsigned short*)sp.p[0];   // W1, >=16KB in either dtype
  int local = 0;
  for(int i = threadIdx.x; i < 8192; i += 256){
    int e = (q[i] >> 7) & 0xFF;
    if(e >= 0xC0) local = 1;
  }
  if(local) atomicOr(&bad, 1);
  __syncthreads();
  int f = bad;
  if(blockIdx.x == 0 && threadIdx.x == 0) *flag = f;
  int b = blockIdx.x;
  const void* src = sp.p[b];
  float* dst = Wc + off[b];
  int n = sz[b];
  for(int i = threadIdx.x; i < n; i += 256) dst[i] = cvt(src, i, f);
}

// ---------------- CSR build: XCD-partitioned bin -> bucket-local scatter ----------------
// phase 1: bin edges into (bucket, partition=blockIdx&7) fixed-capacity slots.
__global__ void k_bin(const int* __restrict__ ei, int* __restrict__ bcur,
                      unsigned* __restrict__ tmp){
  int e = blockIdx.x*256 + threadIdx.x;
  int p = blockIdx.x & (NPART-1);
  if(e < NE){
    int dst = ei[NE + e];
    int src = ei[e];
    int b = dst >> 7;
    int pos = atomicAdd(&bcur[(p*NNB + b)*16], 1);
    if(pos < PCAP) tmp[((size_t)(b*NPART + p) << 9) + pos] = (unsigned)src | ((unsigned)(dst & 127) << 16);
  }
}
// per-bucket: fused exclusive base (scan over prior buckets) -> LDS histogram ->
// local scan -> rowptr/dinv/self-loop/rowend -> scatter
__global__ void k_scatter(const int* __restrict__ bcur,
                          const unsigned* __restrict__ tmp, int* __restrict__ rowptr,
                          int* __restrict__ rowend, float* __restrict__ dinv,
                          unsigned short* __restrict__ srcidx16){
  __shared__ int hist[128];
  __shared__ int lcur[128];
  __shared__ int sh[2][128];
  __shared__ int red[256];
  int b = blockIdx.x;
  int dst0 = b << 7;
  int nd = min(128, NN - dst0);
  int tid = threadIdx.x;
  // exclusive base: sum of all prior buckets' raw cursors + their self loops (128 each)
  int partial = 0;
  for(int i = tid; i < b*NPART; i += 256){
    int b2 = i >> 3, p = i & 7;
    partial += bcur[(p*NNB + b2)*16];
  }
  red[tid] = partial;
  if(tid < 128) hist[tid] = 0;
  __syncthreads();
  for(int off = 128; off; off >>= 1){
    if(tid < off) red[tid] += red[tid + off];
    __syncthreads();
  }
  int base = red[0] + (b << 7);
  // histogram over the bucket's 8 partition streams
  for(int p = 0; p < NPART; p++){
    int cnt = min(bcur[(p*NNB + b)*16], PCAP);
    const unsigned* tp = tmp + ((size_t)(b*NPART + p) << 9);
    for(int i = tid; i < cnt; i += 256) atomicAdd(&hist[tp[i] >> 16], 1);
  }
  __syncthreads();
  // exclusive scan of (hist[t]+1) over 128 dsts (first 128 threads)
  int c = (tid < 128) ? hist[tid] + 1 : 0;     // +1 self loop
  if(tid < 128) sh[0][tid] = c;
  __syncthreads();
  int cur = 0;
  for(int off = 1; off < 128; off <<= 1){
    int nxt = cur^1;
    if(tid < 128){
      int v = sh[cur][tid];
      if(tid >= off) v += sh[cur][tid-off];
      sh[nxt][tid] = v;
    }
    __syncthreads();
    cur = nxt;
  }
  if(tid < nd){
    int rp = base + sh[cur][tid] - c;
    int d = dst0 + tid;
    rowptr[d] = rp;
    srcidx16[rp] = (unsigned short)d;          // self-loop at row start
    rowend[d] = rp + c;                        // c = hist+1
    dinv[d] = rsqrtf((float)c);
    lcur[tid] = rp + 1;
  }
  __syncthreads();
  // scatter
  for(int p = 0; p < NPART; p++){
    int cnt = min(bcur[(p*NNB + b)*16], PCAP);
    const unsigned* tp = tmp + ((size_t)(b*NPART + p) << 9);
    for(int i = tid; i < cnt; i += 256){
      unsigned v = tp[i];
      int pos = atomicAdd(&lcur[v >> 16], 1);
      srcidx16[pos] = (unsigned short)(v & 0xffffu);
    }
  }
}

// ---------------- dense layers ----------------
// PACKED=false: plain bf16 rows (ushort4 store). PACKED=true: head-interleaved
// (h0[c]|h1[c]<<16) rows of KOUT/2 dwords (uint2 store) — feeds GAT gathers directly.
// SCORES=true (requires PACKED): fused per-(row,head) attention scores s,d from the
// register-resident outputs + spread-slot global max (ska[h*32 + blk&31]).
template<int KIN, int KOUT, bool SCALE, bool PACKED, bool SCORES>
__global__ void k_gemm_f(const float* __restrict__ X, const float* __restrict__ W,
                         const float* __restrict__ dinv, void* __restrict__ out,
                         const float* __restrict__ asrc, const float* __restrict__ adst,
                         float* __restrict__ sS, float* __restrict__ sD,
                         unsigned* __restrict__ ska){
  constexpr int TPR = KOUT/4;          // threads per row
  constexpr int R = 256/TPR;           // rows per block
  constexpr int HALF = KOUT/2;
  __shared__ float Wl[KIN*KOUT];
  __shared__ float Xl[R][KIN+4];
  __shared__ unsigned skey[2];
  int tid = threadIdx.x;
  if(SCORES && tid < 2) skey[tid] = 0;
  for(int i = tid; i < KIN*KOUT/4; i += 256)
    ((float4*)Wl)[i] = ((const float4*)W)[i];
  int row0 = blockIdx.x*R;
  for(int i = tid; i < R*KIN/4; i += 256){
    int r = i/(KIN/4), k4 = i - r*(KIN/4);
    int rr = row0 + r;
    float4 v = (rr < NN) ? ((const float4*)(X + (size_t)rr*KIN))[k4]
                         : make_float4(0.f,0.f,0.f,0.f);
    *(float4*)&Xl[r][k4*4] = v;
  }
  __syncthreads();
  int ty = tid/TPR, tx = tid - ty*TPR;
  int row = row0 + ty;
  bool act = row < NN;
  if(!SCORES && !act) return;
  float a0=0.f, a1=0.f, a2=0.f, a3=0.f;
  if(PACKED){
#pragma unroll
    for(int k = 0; k < KIN; k++){
      float xv = Xl[ty][k];
      float2 wa = *(const float2*)&Wl[k*KOUT + 2*tx];
      float2 wb = *(const float2*)&Wl[k*KOUT + HALF + 2*tx];
      a0 += xv*wa.x; a1 += xv*wa.y; a2 += xv*wb.x; a3 += xv*wb.y;
    }
  } else {
#pragma unroll
    for(int k = 0; k < KIN; k++){
      float xv = Xl[ty][k];
      float4 w = *(const float4*)&Wl[k*KOUT + tx*4];
      a0 += xv*w.x; a1 += xv*w.y; a2 += xv*w.z; a3 += xv*w.w;
    }
  }
  float s = SCALE ? dinv[row] : 1.0f;
  if(act){
    if(PACKED){
      uint2 o;
      o.x = (unsigned)f2bf(a0*s) | ((unsigned)f2bf(a2*s) << 16);
      o.y = (unsigned)f2bf(a1*s) | ((unsigned)f2bf(a3*s) << 16);
      *(uint2*)((unsigned*)out + (size_t)row*HALF + 2*tx) = o;
    } else {
      ushort4 o;
      o.x = f2bf(a0*s); o.y = f2bf(a1*s); o.z = f2bf(a2*s); o.w = f2bf(a3*s);
      *(ushort4*)((unsigned short*)out + (size_t)row*KOUT + tx*4) = o;
    }
  }
  if(SCORES){
    // head0 cols (2tx, 2tx+1) = a0,a1 ; head1 cols (2tx, 2tx+1) = a2,a3
    float s0 = a0*asrc[2*tx] + a1*asrc[2*tx+1];
    float d0 = a0*adst[2*tx] + a1*adst[2*tx+1];
    float s1 = a2*asrc[HALF+2*tx] + a3*asrc[HALF+2*tx+1];
    float d1 = a2*adst[HALF+2*tx] + a3*adst[HALF+2*tx+1];
#pragma unroll
    for(int off = 1; off < TPR; off <<= 1){
      s0 += __shfl_xor(s0, off); d0 += __shfl_xor(d0, off);
      s1 += __shfl_xor(s1, off); d1 += __shfl_xor(d1, off);
    }
    if(act && tx == 0){
      *(float2*)(sS + 2*row) = make_float2(s0, s1);
      *(float2*)(sD + 2*row) = make_float2(d0, d1);
      atomicMax(&skey[0], f2key(s0));
      atomicMax(&skey[1], f2key(s1));
    }
    __syncthreads();
    if(tid < 2) atomicMax(&ska[tid*32 + (blockIdx.x & 31)], skey[tid]);
  }
}

template<int KIN, int KOUT, bool SCALE>
__global__ void k_gemm_in(const void* __restrict__ X, const float* __restrict__ W,
                          const float* __restrict__ dinv, unsigned short* __restrict__ Au,
                          const int* __restrict__ flag){
  constexpr int TPR = KOUT/4;
  constexpr int R = 256/TPR;
  __shared__ float Wl[KIN*KOUT];
  __shared__ float Xl[R][KIN+4];
  int tid = threadIdx.x;
  int f = *flag;
  for(int i = tid; i < KIN*KOUT/4; i += 256)
    ((float4*)Wl)[i] = ((const float4*)W)[i];
  int row0 = blockIdx.x*R;
  if(f){
    for(int i = tid; i < R*KIN/4; i += 256){
      int r = i/(KIN/4), k4 = i - r*(KIN/4);
      int rr = row0 + r;
      float4 v = (rr < NN) ? ((const float4*)((const float*)X + (size_t)rr*KIN))[k4]
                           : make_float4(0.f,0.f,0.f,0.f);
      *(float4*)&Xl[r][k4*4] = v;
    }
  } else {
    for(int i = tid; i < R*KIN/4; i += 256){
      int r = i/(KIN/4), k4 = i - r*(KIN/4);
      int rr = row0 + r;
      if(rr < NN){
        ushort4 v = ((const ushort4*)X)[(size_t)rr*(KIN/4) + k4];
        Xl[r][k4*4+0] = __uint_as_float((unsigned)v.x << 16);
        Xl[r][k4*4+1] = __uint_as_float((unsigned)v.y << 16);
        Xl[r][k4*4+2] = __uint_as_float((unsigned)v.z << 16);
        Xl[r][k4*4+3] = __uint_as_float((unsigned)v.w << 16);
      } else {
        Xl[r][k4*4+0] = 0.f; Xl[r][k4*4+1] = 0.f;
        Xl[r][k4*4+2] = 0.f; Xl[r][k4*4+3] = 0.f;
      }
    }
  }
  __syncthreads();
  int ty = tid/TPR, tx = tid - ty*TPR;
  int row = row0 + ty;
  if(row >= NN) return;
  float a0=0.f, a1=0.f, a2=0.f, a3=0.f;
#pragma unroll
  for(int k = 0; k < KIN; k++){
    float xv = Xl[ty][k];
    float4 w = *(const float4*)&Wl[k*KOUT + tx*4];
    a0 += xv*w.x; a1 += xv*w.y; a2 += xv*w.z; a3 += xv*w.w;
  }
  float s = SCALE ? dinv[row] : 1.0f;
  ushort4 o;
  o.x = f2bf(a0*s); o.y = f2bf(a1*s); o.z = f2bf(a2*s); o.w = f2bf(a3*s);
  *(ushort4*)(Au + (size_t)row*KOUT + tx*4) = o;
}

// ---------------- gather aggregations (one wave per dst node) ----------------
// GCN: 8 lanes/edge, 8 edges/iter; row = 64 bf16 = 8 uint4 slots.
__global__ void k_gcn_gather(const int* __restrict__ rowptr, const int* __restrict__ rowend,
                             const unsigned short* __restrict__ srcidx16, const float* __restrict__ dinv,
                             const unsigned* __restrict__ Au32, const float* __restrict__ bias,
                             float* __restrict__ B){
  int wid = threadIdx.x >> 6, lane = threadIdx.x & 63;
  int n = blockIdx.x*4 + wid;
  if(n >= NN) return;
  int s0 = rowptr[n], ne = rowend[n] - s0;
  int o = lane >> 3, c4 = lane & 7;
  float a0=0,a1=0,a2=0,a3=0,a4=0,a5=0,a6=0,a7=0;
  for(int base = 0; base < ne; base += 64){
    int my = base + lane;
    int src = (my < ne) ? (int)srcidx16[s0 + my] : -1;
    int cnt = min(64, ne - base);
    int iters = (cnt + 7) >> 3;
#pragma unroll 4
    for(int j = 0; j < iters; j++){
      int sb = __shfl(src, 8*j + o);
      if(sb >= 0){
        uint4 p = *(const uint4*)(Au32 + (size_t)sb*32 + c4*4);
        a0 += bflo(p.x); a1 += bfhi(p.x);
        a2 += bflo(p.y); a3 += bfhi(p.y);
        a4 += bflo(p.z); a5 += bfhi(p.z);
        a6 += bflo(p.w); a7 += bfhi(p.w);
      }
    }
  }
#pragma unroll
  for(int off = 8; off <= 32; off <<= 1){
    a0 += __shfl_xor(a0, off); a1 += __shfl_xor(a1, off);
    a2 += __shfl_xor(a2, off); a3 += __shfl_xor(a3, off);
    a4 += __shfl_xor(a4, off); a5 += __shfl_xor(a5, off);
    a6 += __shfl_xor(a6, off); a7 += __shfl_xor(a7, off);
  }
  if(o == 0){
    float dn = dinv[n];
    int cb = 8*c4;
    float4 v0, v1;
    v0.x = fmaxf(a0*dn + bias[cb+0], 0.0f);
    v0.y = fmaxf(a1*dn + bias[cb+1], 0.0f);
    v0.z = fmaxf(a2*dn + bias[cb+2], 0.0f);
    v0.w = fmaxf(a3*dn + bias[cb+3], 0.0f);
    v1.x = fmaxf(a4*dn + bias[cb+4], 0.0f);
    v1.y = fmaxf(a5*dn + bias[cb+5], 0.0f);
    v1.z = fmaxf(a6*dn + bias[cb+6], 0.0f);
    v1.w = fmaxf(a7*dn + bias[cb+7], 0.0f);
    *(float4*)(B + (size_t)n*64 + cb)     = v0;
    *(float4*)(B + (size_t)n*64 + cb + 4) = v1;
  }
}

// per-wave reduction of the 32-slot spread max keys (head0 slots [0,32), head1 [32,64))
__device__ __forceinline__ void ska_max2(const unsigned* __restrict__ ska, int lane,
                                         float& m0, float& m1){
  unsigned kk = ska[lane];
#pragma unroll
  for(int off = 1; off <= 16; off <<= 1) kk = max(kk, __shfl_xor(kk, off));
  m0 = key2f(__shfl(kk, 0));
  m1 = key2f(__shfl(kk, 32));
}

// GAT1 (heads=2, C=64, concat): single-pass softmax via global-bound m̂;
// 16 lanes/edge, 4 edges/iter.
__global__ void k_gat1_gather(const int* __restrict__ rowptr, const int* __restrict__ rowend,
                              const unsigned short* __restrict__ srcidx16, const float* __restrict__ sS,
                              const float* __restrict__ sD, const unsigned* __restrict__ Ab,
                              const float* __restrict__ bias, float* __restrict__ B,
                              const unsigned* __restrict__ ska){
  int wid = threadIdx.x >> 6, lane = threadIdx.x & 63;
  int n = blockIdx.x*4 + wid;
  if(n >= NN) return;
  float g0, g1;
  ska_max2(ska, lane, g0, g1);
  int s0 = rowptr[n], ne = rowend[n] - s0;
  float d0 = sD[n*2], d1 = sD[n*2+1];
  float t0 = g0 + d0;  float m0 = t0 > 0.0f ? t0 : 0.2f*t0;
  float t1 = g1 + d1;  float m1 = t1 > 0.0f ? t1 : 0.2f*t1;
  int q = lane >> 4, c4 = lane & 15;
  float z0 = 0.0f, z1 = 0.0f;
  float b0=0,b1=0,b2=0,b3=0, c0=0,c1=0,c2=0,c3=0;
  for(int base = 0; base < ne; base += 64){
    int my = base + lane;
    int src = 0; float w0 = 0.0f, w1 = 0.0f;
    if(my < ne){
      src = (int)srcidx16[s0 + my];
      float2 sv = *(const float2*)(sS + src*2);
      float e0 = sv.x + d0; e0 = e0 > 0.0f ? e0 : 0.2f*e0;
      float e1 = sv.y + d1; e1 = e1 > 0.0f ? e1 : 0.2f*e1;
      w0 = __expf(e0 - m0); w1 = __expf(e1 - m1);
      z0 += w0; z1 += w1;
    }
    int cnt = min(64, ne - base);
    int iters = (cnt + 3) >> 2;
#pragma unroll 4
    for(int j = 0; j < iters; j++){
      int idx = 4*j + q;
      int sb = __shfl(src, idx);
      float a0 = __shfl(w0, idx), a1 = __shfl(w1, idx);
      uint4 p = *(const uint4*)(Ab + (size_t)sb*64 + c4*4);
      b0 += bflo(p.x)*a0; c0 += bfhi(p.x)*a1;
      b1 += bflo(p.y)*a0; c1 += bfhi(p.y)*a1;
      b2 += bflo(p.z)*a0; c2 += bfhi(p.z)*a1;
      b3 += bflo(p.w)*a0; c3 += bfhi(p.w)*a1;
    }
  }
#pragma unroll
  for(int off = 1; off <= 32; off <<= 1){ z0 += __shfl_xor(z0, off); z1 += __shfl_xor(z1, off); }
#pragma unroll
  for(int off = 16; off <= 32; off <<= 1){
    b0 += __shfl_xor(b0, off); b1 += __shfl_xor(b1, off);
    b2 += __shfl_xor(b2, off); b3 += __shfl_xor(b3, off);
    c0 += __shfl_xor(c0, off); c1 += __shfl_xor(c1, off);
    c2 += __shfl_xor(c2, off); c3 += __shfl_xor(c3, off);
  }
  if(q == 0){
    float iz0 = 1.0f/(z0 + 1e-16f), iz1 = 1.0f/(z1 + 1e-16f);
    int cb = 4*c4;
    float4 o0, o1;
    o0.x = fmaxf(b0*iz0 + bias[cb+0], 0.0f);
    o0.y = fmaxf(b1*iz0 + bias[cb+1], 0.0f);
    o0.z = fmaxf(b2*iz0 + bias[cb+2], 0.0f);
    o0.w = fmaxf(b3*iz0 + bias[cb+3], 0.0f);
    o1.x = fmaxf(c0*iz1 + bias[64+cb+0], 0.0f);
    o1.y = fmaxf(c1*iz1 + bias[64+cb+1], 0.0f);
    o1.z = fmaxf(c2*iz1 + bias[64+cb+2], 0.0f);
    o1.w = fmaxf(c3*iz1 + bias[64+cb+3], 0.0f);
    *(float4*)(B + (size_t)n*128 + cb)      = o0;
    *(float4*)(B + (size_t)n*128 + 64 + cb) = o1;
  }
}

// GAT2 (heads=2, C=32, mean) + bias + log_softmax, single-pass softmax;
// 8 lanes/edge, 8 edges/iter.
__global__ void k_gat2_final(const int* __restrict__ rowptr, const int* __restrict__ rowend,
                             const unsigned short* __restrict__ srcidx16, const float* __restrict__ sS,
                             const float* __restrict__ sD, const unsigned* __restrict__ Ab,
                             const float* __restrict__ bias, void* __restrict__ out,
                             const int* __restrict__ flag, const unsigned* __restrict__ ska){
  int wid = threadIdx.x >> 6, lane = threadIdx.x & 63;
  int n = blockIdx.x*4 + wid;
  if(n >= NN) return;
  float g0, g1;
  ska_max2(ska, lane, g0, g1);
  int s0 = rowptr[n], ne = rowend[n] - s0;
  float d0 = sD[n*2], d1 = sD[n*2+1];
  float t0 = g0 + d0;  float m0 = t0 > 0.0f ? t0 : 0.2f*t0;
  float t1 = g1 + d1;  float m1 = t1 > 0.0f ? t1 : 0.2f*t1;
  int o = lane >> 3, c4 = lane & 7;
  float z0 = 0.0f, z1 = 0.0f;
  float b0=0,b1=0,b2=0,b3=0, c0=0,c1=0,c2=0,c3=0;
  for(int base = 0; base < ne; base += 64){
    int my = base + lane;
    int src = 0; float w0 = 0.0f, w1 = 0.0f;
    if(my < ne){
      src = (int)srcidx16[s0 + my];
      float2 sv = *(const float2*)(sS + src*2);
      float e0 = sv.x + d0; e0 = e0 > 0.0f ? e0 : 0.2f*e0;
      float e1 = sv.y + d1; e1 = e1 > 0.0f ? e1 : 0.2f*e1;
      w0 = __expf(e0 - m0); w1 = __expf(e1 - m1);
      z0 += w0; z1 += w1;
    }
    int cnt = min(64, ne - base);
    int iters = (cnt + 7) >> 3;
#pragma unroll 4
    for(int j = 0; j < iters; j++){
      int idx = 8*j + o;
      int sb = __shfl(src, idx);
      float a0 = __shfl(w0, idx), a1 = __shfl(w1, idx);
      uint4 p = *(const uint4*)(Ab + (size_t)sb*32 + c4*4);
      b0 += bflo(p.x)*a0; c0 += bfhi(p.x)*a1;
      b1 += bflo(p.y)*a0; c1 += bfhi(p.y)*a1;
      b2 += bflo(p.z)*a0; c2 += bfhi(p.z)*a1;
      b3 += bflo(p.w)*a0; c3 += bfhi(p.w)*a1;
    }
  }
#pragma unroll
  for(int off = 1; off <= 32; off <<= 1){ z0 += __shfl_xor(z0, off); z1 += __shfl_xor(z1, off); }
#pragma unroll
  for(int off = 8; off <= 32; off <<= 1){
    b0 += __shfl_xor(b0, off); b1 += __shfl_xor(b1, off);
    b2 += __shfl_xor(b2, off); b3 += __shfl_xor(b3, off);
    c0 += __shfl_xor(c0, off); c1 += __shfl_xor(c1, off);
    c2 += __shfl_xor(c2, off); c3 += __shfl_xor(c3, off);
  }
  float iz0 = 1.0f/(z0 + 1e-16f), iz1 = 1.0f/(z1 + 1e-16f);
  int cb = 4*c4;
  float o0 = 0.5f*(b0*iz0 + c0*iz1) + bias[cb+0];
  float o1 = 0.5f*(b1*iz0 + c1*iz1) + bias[cb+1];
  float o2 = 0.5f*(b2*iz0 + c2*iz1) + bias[cb+2];
  float o3 = 0.5f*(b3*iz0 + c3*iz1) + bias[cb+3];
  float mx = fmaxf(fmaxf(o0, o1), fmaxf(o2, o3));
  for(int off = 4; off; off >>= 1) mx = fmaxf(mx, __shfl_xor(mx, off));
  float sm = __expf(o0 - mx) + __expf(o1 - mx) + __expf(o2 - mx) + __expf(o3 - mx);
  for(int off = 4; off; off >>= 1) sm += __shfl_xor(sm, off);
  float lse = mx + __logf(sm);
  if(o == 0){
    if(*flag){
      float4 r;
      r.x = o0 - lse; r.y = o1 - lse; r.z = o2 - lse; r.w = o3 - lse;
      *(float4*)((float*)out + (size_t)n*32 + cb) = r;
    } else {
      uint2 r;
      r.x = (unsigned)f2bf(o0 - lse) | ((unsigned)f2bf(o1 - lse) << 16);
      r.y = (unsigned)f2bf(o2 - lse) | ((unsigned)f2bf(o3 - lse) << 16);
      *(uint2*)((unsigned*)out + (size_t)n*16 + 2*c4) = r;
    }
  }
}

extern "C" void kernel_launch(void* const* d_in, const int* in_sizes, int n_in,
                              void* d_out, int out_size, void* d_ws, size_t ws_size,
                              hipStream_t stream) {
  const void* x   = d_in[0];
  const int*  ei  = (const int*)d_in[1];

  // workspace layout:
  // A-region 25.6MB: Au bf16 [NN*64] (GCN) | Ab u32 [NN*64] at +12.8MB (GAT packed)
  // B[NN*128] f32 | dinv | sS | sD | rowptr | rowend |
  // srcidx16[NT] | SKA[128] | bcur[8*391*16 padded] | tmp[391*8*512] u32 | Wc | flag
  float* A    = (float*)d_ws;
  unsigned short* Au = (unsigned short*)A;
  unsigned* Au32 = (unsigned*)A;
  unsigned* Ab = (unsigned*)(A + (size_t)NN*64);   // +12.8MB
  float* B    = A + (size_t)NN*128;
  float* dinv = B + (size_t)NN*128;
  float* sS   = dinv + NN;
  float* sD   = sS + 2*NN;
  int* rowptr = (int*)(sD + 2*NN);
  int* rowend = rowptr + NN;
  unsigned short* srcidx16 = (unsigned short*)(rowend + NN);
  unsigned* SKA = (unsigned*)(srcidx16 + NT + 2);  // [2 gats][2 heads][32 slots]
  int* bcur   = (int*)(SKA + 128);
  unsigned* tmp = (unsigned*)(bcur + NPART*NNB*16);
  float* Wc   = (float*)(tmp + (size_t)NNB*NPART*PCAP);
  int*  flag  = (int*)(Wc + 29344);

  const float* W1c  = Wc;
  const float* b1c  = Wc + 8192;
  const float* W2c  = Wc + 8256;
  const float* b2c  = Wc + 12352;
  const float* Wg1c = Wc + 12416;
  const float* as1c = Wc + 20608;
  const float* ad1c = Wc + 20736;
  const float* bg1c = Wc + 20864;
  const float* Wg2c = Wc + 20992;
  const float* as2c = Wc + 29184;
  const float* ad2c = Wc + 29248;
  const float* bg2c = Wc + 29312;

  auto nb = [](long long t){ return dim3((unsigned)((t + 255)/256)); };
  dim3 gnodes((NN + 3)/4);      // 4 waves/block, 1 wave per node

  // weight conversion with self-detection (block 0 publishes flag)
  SrcPtrs sp;
  for(int i = 0; i < 12; i++) sp.p[i] = d_in[2 + i];
  k_cvtall<<<12, 256, 0, stream>>>(sp, Wc, flag);

  // single memset covers SKA (512B) + bcur cursors (adjacent)
  hipMemsetAsync(SKA, 0, 512 + NPART*NNB*16*4, stream);

  // CSR build — XCD-partitioned bin, bucket-local scatter with fused base scan
  k_bin<<<nb(NE), 256, 0, stream>>>(ei, bcur, tmp);
  k_scatter<<<NNB, 256, 0, stream>>>(bcur, tmp, rowptr, rowend, dinv, srcidx16);

  // ---- GCN1 ----  (GEMM prescales rows by dinv, writes bf16)
  k_gemm_in<128,64,true><<<dim3((NN+15)/16), 256, 0, stream>>>(x, W1c, dinv, Au, flag);
  k_gcn_gather<<<gnodes, 256, 0, stream>>>(rowptr, rowend, srcidx16, dinv, Au32, b1c, B);

  // ---- GCN2 ----
  k_gemm_f<64,64,true,false,false><<<dim3((NN+15)/16), 256, 0, stream>>>(
      B, W2c, dinv, Au, nullptr, nullptr, nullptr, nullptr, nullptr);
  k_gcn_gather<<<gnodes, 256, 0, stream>>>(rowptr, rowend, srcidx16, dinv, Au32, b2c, B);

  // ---- GAT1: heads=2, C=64, concat ----  (GEMM writes packed + fused scores)
  k_gemm_f<64,128,false,true,true><<<dim3((NN+7)/8), 256, 0, stream>>>(
      B, Wg1c, dinv, Ab, as1c, ad1c, sS, sD, SKA);
  k_gat1_gather<<<gnodes, 256, 0, stream>>>(rowptr, rowend, srcidx16, sS, sD, Ab, bg1c, B, SKA);

  // ---- GAT2: heads=2, C=32, mean + log_softmax ----  (GEMM + fused scores)
  k_gemm_f<128,64,false,true,true><<<dim3((NN+15)/16), 256, 0, stream>>>(
      B, Wg2c, dinv, Ab, as2c, ad2c, sS, sD, SKA + 64);
  k_gat2_final<<<gnodes, 256, 0, stream>>>(rowptr, rowend, srcidx16, sS, sD, Ab, bg2c, d_out, flag, SKA + 64);
}

// Round 3
// 346.098 us; speedup vs baseline: 1.2210x; 1.1959x over previous
//
#include <hip/hip_runtime.h>
#include <hip/hip_bf16.h>

typedef __hip_bfloat16 bf16;
typedef __attribute__((ext_vector_type(8))) short bf16x8;
typedef __attribute__((ext_vector_type(4))) float f32x4;

constexpr int NN = 50000;           // nodes
constexpr int NE = 800000;          // edges (without self loops)
constexpr int NT = NE + NN;         // edges incl self loops
constexpr int NNB  = (NN + 127)/128; // 391 fill buckets (128 dsts each)
constexpr int NPART = 8;             // XCD partitions (blockIdx & 7)
constexpr int PCAP = 512;            // slots per (bucket, partition); mean 256, 16 sigma

// flag-selected load: f32 storage vs bf16 storage
__device__ __forceinline__ float cvt(const void* p, long long i, int f32){
  return f32 ? ((const float*)p)[i] : __bfloat162float(((const bf16*)p)[i]);
}
// bf16 <-> f32 (RNE pack)
__device__ __forceinline__ unsigned short f2bf(float f){
  unsigned u = __float_as_uint(f);
  u += 0x7fffu + ((u >> 16) & 1);
  return (unsigned short)(u >> 16);
}
__device__ __forceinline__ float bflo(unsigned p){ return __uint_as_float(p << 16); }
__device__ __forceinline__ float bfhi(unsigned p){ return __uint_as_float(p & 0xffff0000u); }
__device__ __forceinline__ unsigned packbf(float a, float b){
  return (unsigned)f2bf(a) | ((unsigned)f2bf(b) << 16);
}
// monotone float<->uint key for atomicMax
__device__ __forceinline__ unsigned f2key(float f){
  unsigned u = __float_as_uint(f);
  return (u & 0x80000000u) ? ~u : (u | 0x80000000u);
}
__device__ __forceinline__ float key2f(unsigned k){
  unsigned u = (k & 0x80000000u) ? (k & 0x7fffffffu) : ~k;
  return __uint_as_float(u);
}

struct SrcPtrs { const void* p[12]; };
// Weight conversion (blocks 0-11: f32 copies for biases/attn vecs; block 0 publishes flag)
// + MFMA fragmentation (blocks 12-15): W -> hi/lo bf16 in lane order
// frag fr = nf*KF + kf; elem: lane l, i -> W[kf*32 + (l>>4)*8 + i][nf*16 + (l&15)]
__global__ void k_cvtall(SrcPtrs sp, float* __restrict__ Wc,
                         unsigned short* __restrict__ Wf, int* __restrict__ flag){
  const int sz[12]  = {8192,64,4096,64,8192,128,128,128,8192,64,64,32};
  const int off[12] = {0,8192,8256,12352,12416,20608,20736,20864,20992,29184,29248,29312};
  __shared__ int bad;
  int tid = threadIdx.x;
  if(tid == 0) bad = 0;
  __syncthreads();
  const unsigned short* q = (const unsigned short*)sp.p[0];   // W1, >=16KB in either dtype
  int local = 0;
  for(int i = tid; i < 8192; i += 256){
    int e = (q[i] >> 7) & 0xFF;
    if(e >= 0xC0) local = 1;
  }
  if(local) atomicOr(&bad, 1);
  __syncthreads();
  int f = bad;
  int b = blockIdx.x;
  if(b == 0 && tid == 0) *flag = f;
  if(b < 12){
    const void* src = sp.p[b];
    float* dst = Wc + off[b];
    int n = sz[b];
    for(int i = tid; i < n; i += 256) dst[i] = cvt(src, i, f);
  } else {
    int g = b - 12;
    const int KK[4]   = {128, 64, 64, 128};
    const int NNo[4]  = {64, 64, 128, 64};
    const int srcI[4] = {0, 2, 4, 8};            // W1, W2, Wg1, Wg2 in sp.p
    const int foff[4] = {0, 16384, 24576, 40960};
    int K = KK[g], N = NNo[g], KF = K/32;
    const void* src = sp.p[srcI[g]];
    unsigned short* dh = Wf + foff[g];
    unsigned short* dl = dh + K*N;
    int tot = K*N;
    for(int idx = tid; idx < tot; idx += 256){
      int i = idx & 7, lane = (idx >> 3) & 63, fr = idx >> 9;
      int kf = fr % KF, nf = fr / KF;
      int k = kf*32 + ((lane >> 4) << 3) + i;
      int n = nf*16 + (lane & 15);
      float w = cvt(src, (long long)k*N + n, f);
      unsigned short h = f2bf(w);
      dh[idx] = h;
      dl[idx] = f2bf(w - __uint_as_float((unsigned)h << 16));
    }
  }
}

// ---------------- CSR build: XCD-partitioned bin -> bucket-local scatter ----------------
__global__ void k_bin(const int* __restrict__ ei, int* __restrict__ bcur,
                      unsigned* __restrict__ tmp){
  int e = blockIdx.x*256 + threadIdx.x;
  int p = blockIdx.x & (NPART-1);
  if(e < NE){
    int dst = ei[NE + e];
    int src = ei[e];
    int b = dst >> 7;
    int pos = atomicAdd(&bcur[(p*NNB + b)*16], 1);
    if(pos < PCAP) tmp[((size_t)(b*NPART + p) << 9) + pos] = (unsigned)src | ((unsigned)(dst & 127) << 16);
  }
}
__global__ void k_scatter(const int* __restrict__ bcur,
                          const unsigned* __restrict__ tmp, int* __restrict__ rowptr,
                          int* __restrict__ rowend, float* __restrict__ dinv,
                          unsigned short* __restrict__ srcidx16){
  __shared__ int hist[128];
  __shared__ int lcur[128];
  __shared__ int sh[2][128];
  __shared__ int red[256];
  int b = blockIdx.x;
  int dst0 = b << 7;
  int nd = min(128, NN - dst0);
  int tid = threadIdx.x;
  int partial = 0;
  for(int i = tid; i < b*NPART; i += 256){
    int b2 = i >> 3, p = i & 7;
    partial += bcur[(p*NNB + b2)*16];
  }
  red[tid] = partial;
  if(tid < 128) hist[tid] = 0;
  __syncthreads();
  for(int off = 128; off; off >>= 1){
    if(tid < off) red[tid] += red[tid + off];
    __syncthreads();
  }
  int base = red[0] + (b << 7);
  for(int p = 0; p < NPART; p++){
    int cnt = min(bcur[(p*NNB + b)*16], PCAP);
    const unsigned* tp = tmp + ((size_t)(b*NPART + p) << 9);
    for(int i = tid; i < cnt; i += 256) atomicAdd(&hist[tp[i] >> 16], 1);
  }
  __syncthreads();
  int c = (tid < 128) ? hist[tid] + 1 : 0;     // +1 self loop
  if(tid < 128) sh[0][tid] = c;
  __syncthreads();
  int cur = 0;
  for(int off = 1; off < 128; off <<= 1){
    int nxt = cur^1;
    if(tid < 128){
      int v = sh[cur][tid];
      if(tid >= off) v += sh[cur][tid-off];
      sh[nxt][tid] = v;
    }
    __syncthreads();
    cur = nxt;
  }
  if(tid < nd){
    int rp = base + sh[cur][tid] - c;
    int d = dst0 + tid;
    rowptr[d] = rp;
    srcidx16[rp] = (unsigned short)d;
    rowend[d] = rp + c;
    dinv[d] = rsqrtf((float)c);
    lcur[tid] = rp + 1;
  }
  __syncthreads();
  for(int p = 0; p < NPART; p++){
    int cnt = min(bcur[(p*NNB + b)*16], PCAP);
    const unsigned* tp = tmp + ((size_t)(b*NPART + p) << 9);
    for(int i = tid; i < cnt; i += 256){
      unsigned v = tp[i];
      int pos = atomicAdd(&lcur[v >> 16], 1);
      srcidx16[pos] = (unsigned short)(v & 0xffffu);
    }
  }
}

// ---------------- MFMA dense layers ----------------
// 64 rows/block, 4 waves (16 rows each), all KOUT cols per wave.
// A-frags loaded directly from global (bf16 rows; or f32/bf16 by flag when MODE=1).
// W pre-fragmented hi/lo bf16 (hi+lo split keeps weight precision ~f32).
// PACKC==0: plain bf16 out rows (optional dinv prescale).
// PACKC==C: head-interleaved u32 rows (h0[c]|h1[c]<<16) + fused attention scores.
template<int KIN, int KOUT, bool SCALE, int PACKC, int MODE>
__global__ void k_mfma(const void* __restrict__ X, const unsigned short* __restrict__ Wh,
                       const unsigned short* __restrict__ Wl,
                       const float* __restrict__ dinv, void* __restrict__ out,
                       const float* __restrict__ asrc, const float* __restrict__ adst,
                       float* __restrict__ sS, float* __restrict__ sD,
                       unsigned* __restrict__ ska, const int* __restrict__ flag){
  constexpr int KF = KIN/32;
  constexpr int NF = KOUT/16;
  constexpr int PITCH = KOUT + 1;
  __shared__ float Cl[64*PITCH];
  __shared__ unsigned skey[2];
  int tid = threadIdx.x;
  if(PACKC > 0 && tid < 2) skey[tid] = 0;
  int wv = tid >> 6, lane = tid & 63;
  int lr = lane >> 4, lc = lane & 15;
  int row0 = blockIdx.x*64;
  int arow = row0 + wv*16 + lc;
  if(arow >= NN) arow = NN - 1;                  // clamp: results discarded
  int f = (MODE == 1) ? *flag : 0;
  const char* xb = (const char*)X;
  f32x4 acc[NF];
#pragma unroll
  for(int nf = 0; nf < NF; nf++) acc[nf] = (f32x4){0.f,0.f,0.f,0.f};
#pragma unroll
  for(int kf = 0; kf < KF; kf++){
    bf16x8 a;
    if(MODE == 1 && f){
      const float* xf = (const float*)xb + (size_t)arow*KIN + kf*32 + lr*8;
      float4 u = *(const float4*)xf;
      float4 v = *(const float4*)(xf + 4);
      a[0]=(short)f2bf(u.x); a[1]=(short)f2bf(u.y); a[2]=(short)f2bf(u.z); a[3]=(short)f2bf(u.w);
      a[4]=(short)f2bf(v.x); a[5]=(short)f2bf(v.y); a[6]=(short)f2bf(v.z); a[7]=(short)f2bf(v.w);
    } else {
      a = *(const bf16x8*)(xb + (size_t)arow*(KIN*2) + kf*64 + lr*16);
    }
#pragma unroll
    for(int nf = 0; nf < NF; nf++){
      int fr = nf*KF + kf;
      bf16x8 wh = *(const bf16x8*)((const short*)Wh + (fr << 9) + (lane << 3));
      bf16x8 wl = *(const bf16x8*)((const short*)Wl + (fr << 9) + (lane << 3));
      acc[nf] = __builtin_amdgcn_mfma_f32_16x16x32_bf16(a, wh, acc[nf], 0, 0, 0);
      acc[nf] = __builtin_amdgcn_mfma_f32_16x16x32_bf16(a, wl, acc[nf], 0, 0, 0);
    }
  }
  // C-frags -> LDS (C/D layout: col=lane&15, row=(lane>>4)*4+reg)
#pragma unroll
  for(int nf = 0; nf < NF; nf++)
#pragma unroll
    for(int r = 0; r < 4; r++)
      Cl[(wv*16 + lr*4 + r)*PITCH + nf*16 + lc] = acc[nf][r];
  __syncthreads();
  // phase 2: 4 threads per row
  int row = tid >> 2, q = tid & 3;
  int grow = row0 + row;
  bool valid = grow < NN;
  const float* cr = &Cl[row*PITCH];
  if constexpr (PACKC == 0){
    float s = SCALE ? (valid ? dinv[grow] : 0.0f) : 1.0f;
    unsigned ov[8];
#pragma unroll
    for(int j = 0; j < 8; j++)
      ov[j] = packbf(cr[q*16 + 2*j]*s, cr[q*16 + 2*j + 1]*s);
    if(valid){
      unsigned* op = (unsigned*)out + (size_t)grow*(KOUT/2) + q*8;
      *(uint4*)op       = make_uint4(ov[0],ov[1],ov[2],ov[3]);
      *(uint4*)(op + 4) = make_uint4(ov[4],ov[5],ov[6],ov[7]);
    }
  } else {
    constexpr int C = PACKC;
    constexpr int CT = C/4;                     // cols per thread
    float s0=0.f, d0=0.f, s1=0.f, d1=0.f;
    unsigned ov[CT];
#pragma unroll
    for(int j = 0; j < CT; j++){
      int c = q*CT + j;
      float a = cr[c], bb = cr[C + c];
      ov[j] = packbf(a, bb);
      s0 += a*asrc[c];      d0 += a*adst[c];
      s1 += bb*asrc[C + c]; d1 += bb*adst[C + c];
    }
    if(valid){
      unsigned* op = (unsigned*)out + (size_t)grow*C + q*CT;
#pragma unroll
      for(int j4 = 0; j4 < CT/4; j4++)
        *(uint4*)(op + 4*j4) = make_uint4(ov[4*j4],ov[4*j4+1],ov[4*j4+2],ov[4*j4+3]);
    }
    s0 += __shfl_xor(s0,1); s0 += __shfl_xor(s0,2);
    d0 += __shfl_xor(d0,1); d0 += __shfl_xor(d0,2);
    s1 += __shfl_xor(s1,1); s1 += __shfl_xor(s1,2);
    d1 += __shfl_xor(d1,1); d1 += __shfl_xor(d1,2);
    if(valid && q == 0){
      *(float2*)(sS + 2*grow) = make_float2(s0, s1);
      *(float2*)(sD + 2*grow) = make_float2(d0, d1);
      atomicMax(&skey[0], f2key(s0));
      atomicMax(&skey[1], f2key(s1));
    }
    __syncthreads();
    if(tid < 2) atomicMax(&ska[tid*32 + (blockIdx.x & 31)], skey[tid]);
  }
}

// ---------------- gather aggregations (one wave per dst node) ----------------
// GCN: 8 lanes/edge, 8 edges/iter; row = 64 bf16 = 8 uint4 slots. Writes bf16 B.
__global__ void k_gcn_gather(const int* __restrict__ rowptr, const int* __restrict__ rowend,
                             const unsigned short* __restrict__ srcidx16, const float* __restrict__ dinv,
                             const unsigned* __restrict__ Au32, const float* __restrict__ bias,
                             unsigned* __restrict__ B){
  int wid = threadIdx.x >> 6, lane = threadIdx.x & 63;
  int n = blockIdx.x*4 + wid;
  if(n >= NN) return;
  int s0 = rowptr[n], ne = rowend[n] - s0;
  int o = lane >> 3, c4 = lane & 7;
  float a0=0,a1=0,a2=0,a3=0,a4=0,a5=0,a6=0,a7=0;
  for(int base = 0; base < ne; base += 64){
    int my = base + lane;
    int src = (my < ne) ? (int)srcidx16[s0 + my] : -1;
    int cnt = min(64, ne - base);
    int iters = (cnt + 7) >> 3;
#pragma unroll 4
    for(int j = 0; j < iters; j++){
      int sb = __shfl(src, 8*j + o);
      if(sb >= 0){
        uint4 p = *(const uint4*)(Au32 + (size_t)sb*32 + c4*4);
        a0 += bflo(p.x); a1 += bfhi(p.x);
        a2 += bflo(p.y); a3 += bfhi(p.y);
        a4 += bflo(p.z); a5 += bfhi(p.z);
        a6 += bflo(p.w); a7 += bfhi(p.w);
      }
    }
  }
#pragma unroll
  for(int off = 8; off <= 32; off <<= 1){
    a0 += __shfl_xor(a0, off); a1 += __shfl_xor(a1, off);
    a2 += __shfl_xor(a2, off); a3 += __shfl_xor(a3, off);
    a4 += __shfl_xor(a4, off); a5 += __shfl_xor(a5, off);
    a6 += __shfl_xor(a6, off); a7 += __shfl_xor(a7, off);
  }
  if(o == 0){
    float dn = dinv[n];
    int cb = 8*c4;
    uint4 r;
    r.x = packbf(fmaxf(a0*dn + bias[cb+0], 0.0f), fmaxf(a1*dn + bias[cb+1], 0.0f));
    r.y = packbf(fmaxf(a2*dn + bias[cb+2], 0.0f), fmaxf(a3*dn + bias[cb+3], 0.0f));
    r.z = packbf(fmaxf(a4*dn + bias[cb+4], 0.0f), fmaxf(a5*dn + bias[cb+5], 0.0f));
    r.w = packbf(fmaxf(a6*dn + bias[cb+6], 0.0f), fmaxf(a7*dn + bias[cb+7], 0.0f));
    *(uint4*)(B + (size_t)n*32 + c4*4) = r;
  }
}

// per-wave reduction of the 32-slot spread max keys (head0 slots [0,32), head1 [32,64))
__device__ __forceinline__ void ska_max2(const unsigned* __restrict__ ska, int lane,
                                         float& m0, float& m1){
  unsigned kk = ska[lane];
#pragma unroll
  for(int off = 1; off <= 16; off <<= 1) kk = max(kk, __shfl_xor(kk, off));
  m0 = key2f(__shfl(kk, 0));
  m1 = key2f(__shfl(kk, 32));
}

// GAT1 (heads=2, C=64, concat): single-pass softmax via global-bound m̂;
// 16 lanes/edge, 4 edges/iter. Writes bf16 B (128 cols).
__global__ void k_gat1_gather(const int* __restrict__ rowptr, const int* __restrict__ rowend,
                              const unsigned short* __restrict__ srcidx16, const float* __restrict__ sS,
                              const float* __restrict__ sD, const unsigned* __restrict__ Ab,
                              const float* __restrict__ bias, unsigned* __restrict__ B,
                              const unsigned* __restrict__ ska){
  int wid = threadIdx.x >> 6, lane = threadIdx.x & 63;
  int n = blockIdx.x*4 + wid;
  if(n >= NN) return;
  float g0, g1;
  ska_max2(ska, lane, g0, g1);
  int s0 = rowptr[n], ne = rowend[n] - s0;
  float d0 = sD[n*2], d1 = sD[n*2+1];
  float t0 = g0 + d0;  float m0 = t0 > 0.0f ? t0 : 0.2f*t0;
  float t1 = g1 + d1;  float m1 = t1 > 0.0f ? t1 : 0.2f*t1;
  int q = lane >> 4, c4 = lane & 15;
  float z0 = 0.0f, z1 = 0.0f;
  float b0=0,b1=0,b2=0,b3=0, c0=0,c1=0,c2=0,c3=0;
  for(int base = 0; base < ne; base += 64){
    int my = base + lane;
    int src = 0; float w0 = 0.0f, w1 = 0.0f;
    if(my < ne){
      src = (int)srcidx16[s0 + my];
      float2 sv = *(const float2*)(sS + src*2);
      float e0 = sv.x + d0; e0 = e0 > 0.0f ? e0 : 0.2f*e0;
      float e1 = sv.y + d1; e1 = e1 > 0.0f ? e1 : 0.2f*e1;
      w0 = __expf(e0 - m0); w1 = __expf(e1 - m1);
      z0 += w0; z1 += w1;
    }
    int cnt = min(64, ne - base);
    int iters = (cnt + 3) >> 2;
#pragma unroll 4
    for(int j = 0; j < iters; j++){
      int idx = 4*j + q;
      int sb = __shfl(src, idx);
      float a0 = __shfl(w0, idx), a1 = __shfl(w1, idx);
      uint4 p = *(const uint4*)(Ab + (size_t)sb*64 + c4*4);
      b0 += bflo(p.x)*a0; c0 += bfhi(p.x)*a1;
      b1 += bflo(p.y)*a0; c1 += bfhi(p.y)*a1;
      b2 += bflo(p.z)*a0; c2 += bfhi(p.z)*a1;
      b3 += bflo(p.w)*a0; c3 += bfhi(p.w)*a1;
    }
  }
#pragma unroll
  for(int off = 1; off <= 32; off <<= 1){ z0 += __shfl_xor(z0, off); z1 += __shfl_xor(z1, off); }
#pragma unroll
  for(int off = 16; off <= 32; off <<= 1){
    b0 += __shfl_xor(b0, off); b1 += __shfl_xor(b1, off);
    b2 += __shfl_xor(b2, off); b3 += __shfl_xor(b3, off);
    c0 += __shfl_xor(c0, off); c1 += __shfl_xor(c1, off);
    c2 += __shfl_xor(c2, off); c3 += __shfl_xor(c3, off);
  }
  if(q == 0){
    float iz0 = 1.0f/(z0 + 1e-16f), iz1 = 1.0f/(z1 + 1e-16f);
    int cb = 4*c4;
    uint2 r0, r1;
    r0.x = packbf(fmaxf(b0*iz0 + bias[cb+0], 0.0f), fmaxf(b1*iz0 + bias[cb+1], 0.0f));
    r0.y = packbf(fmaxf(b2*iz0 + bias[cb+2], 0.0f), fmaxf(b3*iz0 + bias[cb+3], 0.0f));
    r1.x = packbf(fmaxf(c0*iz1 + bias[64+cb+0], 0.0f), fmaxf(c1*iz1 + bias[64+cb+1], 0.0f));
    r1.y = packbf(fmaxf(c2*iz1 + bias[64+cb+2], 0.0f), fmaxf(c3*iz1 + bias[64+cb+3], 0.0f));
    *(uint2*)(B + (size_t)n*64 + 2*c4)      = r0;    // head0: cols 0..63
    *(uint2*)(B + (size_t)n*64 + 32 + 2*c4) = r1;    // head1: cols 64..127
  }
}

// GAT2 (heads=2, C=32, mean) + bias + log_softmax, single-pass softmax;
// 8 lanes/edge, 8 edges/iter.
__global__ void k_gat2_final(const int* __restrict__ rowptr, const int* __restrict__ rowend,
                             const unsigned short* __restrict__ srcidx16, const float* __restrict__ sS,
                             const float* __restrict__ sD, const unsigned* __restrict__ Ab,
                             const float* __restrict__ bias, void* __restrict__ out,
                             const int* __restrict__ flag, const unsigned* __restrict__ ska){
  int wid = threadIdx.x >> 6, lane = threadIdx.x & 63;
  int n = blockIdx.x*4 + wid;
  if(n >= NN) return;
  float g0, g1;
  ska_max2(ska, lane, g0, g1);
  int s0 = rowptr[n], ne = rowend[n] - s0;
  float d0 = sD[n*2], d1 = sD[n*2+1];
  float t0 = g0 + d0;  float m0 = t0 > 0.0f ? t0 : 0.2f*t0;
  float t1 = g1 + d1;  float m1 = t1 > 0.0f ? t1 : 0.2f*t1;
  int o = lane >> 3, c4 = lane & 7;
  float z0 = 0.0f, z1 = 0.0f;
  float b0=0,b1=0,b2=0,b3=0, c0=0,c1=0,c2=0,c3=0;
  for(int base = 0; base < ne; base += 64){
    int my = base + lane;
    int src = 0; float w0 = 0.0f, w1 = 0.0f;
    if(my < ne){
      src = (int)srcidx16[s0 + my];
      float2 sv = *(const float2*)(sS + src*2);
      float e0 = sv.x + d0; e0 = e0 > 0.0f ? e0 : 0.2f*e0;
      float e1 = sv.y + d1; e1 = e1 > 0.0f ? e1 : 0.2f*e1;
      w0 = __expf(e0 - m0); w1 = __expf(e1 - m1);
      z0 += w0; z1 += w1;
    }
    int cnt = min(64, ne - base);
    int iters = (cnt + 7) >> 3;
#pragma unroll 4
    for(int j = 0; j < iters; j++){
      int idx = 8*j + o;
      int sb = __shfl(src, idx);
      float a0 = __shfl(w0, idx), a1 = __shfl(w1, idx);
      uint4 p = *(const uint4*)(Ab + (size_t)sb*32 + c4*4);
      b0 += bflo(p.x)*a0; c0 += bfhi(p.x)*a1;
      b1 += bflo(p.y)*a0; c1 += bfhi(p.y)*a1;
      b2 += bflo(p.z)*a0; c2 += bfhi(p.z)*a1;
      b3 += bflo(p.w)*a0; c3 += bfhi(p.w)*a1;
    }
  }
#pragma unroll
  for(int off = 1; off <= 32; off <<= 1){ z0 += __shfl_xor(z0, off); z1 += __shfl_xor(z1, off); }
#pragma unroll
  for(int off = 8; off <= 32; off <<= 1){
    b0 += __shfl_xor(b0, off); b1 += __shfl_xor(b1, off);
    b2 += __shfl_xor(b2, off); b3 += __shfl_xor(b3, off);
    c0 += __shfl_xor(c0, off); c1 += __shfl_xor(c1, off);
    c2 += __shfl_xor(c2, off); c3 += __shfl_xor(c3, off);
  }
  float iz0 = 1.0f/(z0 + 1e-16f), iz1 = 1.0f/(z1 + 1e-16f);
  int cb = 4*c4;
  float o0 = 0.5f*(b0*iz0 + c0*iz1) + bias[cb+0];
  float o1 = 0.5f*(b1*iz0 + c1*iz1) + bias[cb+1];
  float o2 = 0.5f*(b2*iz0 + c2*iz1) + bias[cb+2];
  float o3 = 0.5f*(b3*iz0 + c3*iz1) + bias[cb+3];
  float mx = fmaxf(fmaxf(o0, o1), fmaxf(o2, o3));
  for(int off = 4; off; off >>= 1) mx = fmaxf(mx, __shfl_xor(mx, off));
  float sm = __expf(o0 - mx) + __expf(o1 - mx) + __expf(o2 - mx) + __expf(o3 - mx);
  for(int off = 4; off; off >>= 1) sm += __shfl_xor(sm, off);
  float lse = mx + __logf(sm);
  if(o == 0){
    if(*flag){
      float4 r;
      r.x = o0 - lse; r.y = o1 - lse; r.z = o2 - lse; r.w = o3 - lse;
      *(float4*)((float*)out + (size_t)n*32 + cb) = r;
    } else {
      uint2 r;
      r.x = packbf(o0 - lse, o1 - lse);
      r.y = packbf(o2 - lse, o3 - lse);
      *(uint2*)((unsigned*)out + (size_t)n*16 + 2*c4) = r;
    }
  }
}

extern "C" void kernel_launch(void* const* d_in, const int* in_sizes, int n_in,
                              void* d_out, int out_size, void* d_ws, size_t ws_size,
                              hipStream_t stream) {
  const void* x   = d_in[0];
  const int*  ei  = (const int*)d_in[1];

  // workspace layout:
  // A-region 25.6MB: Au bf16 [NN*64] (GCN) | Ab u32 [NN*64] at +12.8MB (GAT packed)
  // B[NN*128] bf16 (region reserved as f32-sized) | dinv | sS | sD | rowptr | rowend |
  // srcidx16[NT] | SKA[128] | bcur | tmp | Wc | flag | Wf (frag'd hi/lo bf16)
  float* A    = (float*)d_ws;
  unsigned short* Au = (unsigned short*)A;
  unsigned* Au32 = (unsigned*)A;
  unsigned* Ab = (unsigned*)(A + (size_t)NN*64);   // +12.8MB
  float* B    = A + (size_t)NN*128;
  float* dinv = B + (size_t)NN*128;
  float* sS   = dinv + NN;
  float* sD   = sS + 2*NN;
  int* rowptr = (int*)(sD + 2*NN);
  int* rowend = rowptr + NN;
  unsigned short* srcidx16 = (unsigned short*)(rowend + NN);
  unsigned* SKA = (unsigned*)(srcidx16 + NT + 2);  // [2 gats][2 heads][32 slots]
  int* bcur   = (int*)(SKA + 128);
  unsigned* tmp = (unsigned*)(bcur + NPART*NNB*16);
  float* Wc   = (float*)(tmp + (size_t)NNB*NPART*PCAP);
  int*  flag  = (int*)(Wc + 29344);
  uintptr_t wfp = ((uintptr_t)(flag + 1) + 15) & ~(uintptr_t)15;
  unsigned short* Wf = (unsigned short*)wfp;       // 57344 ushorts (hi/lo frags)

  const float* b1c  = Wc + 8192;
  const float* b2c  = Wc + 12352;
  const float* as1c = Wc + 20608;
  const float* ad1c = Wc + 20736;
  const float* bg1c = Wc + 20864;
  const float* as2c = Wc + 29184;
  const float* ad2c = Wc + 29248;
  const float* bg2c = Wc + 29312;

  auto nb = [](long long t){ return dim3((unsigned)((t + 255)/256)); };
  dim3 gnodes((NN + 3)/4);      // 4 waves/block, 1 wave per node
  dim3 g64((NN + 63)/64);       // MFMA GEMM: 64 rows/block

  SrcPtrs sp;
  for(int i = 0; i < 12; i++) sp.p[i] = d_in[2 + i];
  k_cvtall<<<16, 256, 0, stream>>>(sp, Wc, Wf, flag);

  // single memset covers SKA (512B) + bcur cursors (adjacent)
  (void)hipMemsetAsync(SKA, 0, 512 + NPART*NNB*16*4, stream);

  k_bin<<<nb(NE), 256, 0, stream>>>(ei, bcur, tmp);
  k_scatter<<<NNB, 256, 0, stream>>>(bcur, tmp, rowptr, rowend, dinv, srcidx16);

  // ---- GCN1 ----  (MFMA GEMM prescales rows by dinv, writes bf16)
  k_mfma<128,64,true,0,1><<<g64, 256, 0, stream>>>(
      x, Wf, Wf + 8192, dinv, Au, nullptr, nullptr, nullptr, nullptr, nullptr, flag);
  k_gcn_gather<<<gnodes, 256, 0, stream>>>(rowptr, rowend, srcidx16, dinv, Au32, b1c, (unsigned*)B);

  // ---- GCN2 ----
  k_mfma<64,64,true,0,0><<<g64, 256, 0, stream>>>(
      B, Wf + 16384, Wf + 20480, dinv, Au, nullptr, nullptr, nullptr, nullptr, nullptr, flag);
  k_gcn_gather<<<gnodes, 256, 0, stream>>>(rowptr, rowend, srcidx16, dinv, Au32, b2c, (unsigned*)B);

  // ---- GAT1: heads=2, C=64, concat ----  (MFMA GEMM, packed out + fused scores)
  k_mfma<64,128,false,64,0><<<g64, 256, 0, stream>>>(
      B, Wf + 24576, Wf + 32768, dinv, Ab, as1c, ad1c, sS, sD, SKA, flag);
  k_gat1_gather<<<gnodes, 256, 0, stream>>>(rowptr, rowend, srcidx16, sS, sD, Ab, bg1c, (unsigned*)B, SKA);

  // ---- GAT2: heads=2, C=32, mean + log_softmax ----
  k_mfma<128,64,false,32,0><<<g64, 256, 0, stream>>>(
      B, Wf + 40960, Wf + 49152, dinv, Ab, as2c, ad2c, sS, sD, SKA + 64, flag);
  k_gat2_final<<<gnodes, 256, 0, stream>>>(rowptr, rowend, srcidx16, sS, sD, Ab, bg2c, d_out, flag, SKA + 64);
}